// Round 7
// baseline (134.877 us; speedup 1.0000x reference)
//
#include <hip/hip_runtime.h>

#define NDIM 64   // D
#define FDIM 128  // 2D

typedef _Float16 half8  __attribute__((ext_vector_type(8)));
typedef _Float16 half4v __attribute__((ext_vector_type(4)));
typedef float    float4v __attribute__((ext_vector_type(4)));

// ---------------------------------------------------------------------------
// Prep: Wcomb[j][k] (f16, [128][64]) = j<64 ? W1[j][k] : W1[j-64][64+k]
// (UNCHANGED from round 6)
// ---------------------------------------------------------------------------
__global__ __launch_bounds__(256) void prep_wcomb_kernel(
    const float* __restrict__ W1, _Float16* __restrict__ Wcomb)
{
    int i = blockIdx.x * blockDim.x + threadIdx.x;   // 8192 = 128*64
    if (i >= FDIM * NDIM) return;
    int j = i >> 6;
    int k = i & 63;
    float v = (j < NDIM) ? W1[j * FDIM + k] : W1[(j - NDIM) * FDIM + NDIM + k];
    Wcomb[i] = (_Float16)v;
}

// ---------------------------------------------------------------------------
// Kernel 1: node half-layers via MFMA. (UNCHANGED from round 6)
//   Yab[n][j]    = b1[j] + sum_k x[n][k] * W1[j][k]        (j < 64)
//   Yab[n][64+j] =         sum_k x[n][k] * W1[j][64+k]
// ---------------------------------------------------------------------------
__global__ __launch_bounds__(256) void node_gemm_kernel(
    const float* __restrict__ x,        // [N][64]
    const _Float16* __restrict__ Wcomb, // [128][64]
    const float* __restrict__ b1,       // [64]
    _Float16* __restrict__ Yab,         // [N][128]
    int N)
{
    const int wave = threadIdx.x >> 6;
    const int lane = threadIdx.x & 63;
    const int c = lane & 15;
    const int g = lane >> 4;

    const int node0 = (blockIdx.x * 4 + wave) * 16;
    if (node0 >= N) return;

    half8 Bf[2];
    #pragma unroll
    for (int kk = 0; kk < 2; kk++) {
        const float* bp = x + (size_t)(node0 + c) * NDIM + kk * 32 + g * 8;
        float4v b0 = *(const float4v*)bp;
        float4v b1v_ = *(const float4v*)(bp + 4);
        half8 B;
        B[0] = (_Float16)b0[0]; B[1] = (_Float16)b0[1];
        B[2] = (_Float16)b0[2]; B[3] = (_Float16)b0[3];
        B[4] = (_Float16)b1v_[0]; B[5] = (_Float16)b1v_[1];
        B[6] = (_Float16)b1v_[2]; B[7] = (_Float16)b1v_[3];
        Bf[kk] = B;
    }

    float4v C[8];
    #pragma unroll
    for (int mt = 0; mt < 8; mt++) C[mt] = (float4v){0.f, 0.f, 0.f, 0.f};

    #pragma unroll
    for (int kk = 0; kk < 2; kk++) {
        #pragma unroll
        for (int mt = 0; mt < 8; mt++) {
            half8 Af = *(const half8*)(Wcomb + (size_t)(mt * 16 + c) * NDIM
                                       + kk * 32 + g * 8);
            C[mt] = __builtin_amdgcn_mfma_f32_16x16x32_f16(Af, Bf[kk], C[mt], 0, 0, 0);
        }
    }

    #pragma unroll
    for (int mt = 0; mt < 8; mt++) {
        float4v badd = (float4v){0.f, 0.f, 0.f, 0.f};
        if (mt < 4) badd = *(const float4v*)(b1 + mt * 16 + g * 4);
        half4v o;
        #pragma unroll
        for (int r = 0; r < 4; r++) o[r] = (_Float16)(C[mt][r] + badd[r]);
        *(half4v*)(Yab + (size_t)(node0 + c) * FDIM + mt * 16 + g * 4) = o;
    }
}

// ---------------------------------------------------------------------------
// Kernel 2 (v3): per-edge combine, MFMA layer-2, NO shuffles.
// Wave = 4 tiles of 16 edges. Lane (c = edge-in-tile, g = k-group).
// Gather: per (tile, kk, side) each lane loads 16 B; 4 lanes/edge cover 64 B
// contiguous. All 8 index loads + 16 gathers are independent -> deep MLP.
// H = relu(Ya[s] + Yb[d]) built with v_pk_add/max_f16 directly in MFMA
// A-layout; layer-2 dot = mfma(H, W2bcast): every C column holds the result.
//   out[e] = b2 + sum_j W2[j] * relu(Yab[s][j] + Yab[d][64+j])
// ---------------------------------------------------------------------------
__global__ __launch_bounds__(256) void edge_combine_kernel(
    const _Float16* __restrict__ Yab,  // [N][128]
    const int* __restrict__ ei,        // [2E]
    const float* __restrict__ W2,      // [64]
    const float* __restrict__ b2,      // [1]
    float* __restrict__ out,           // [E]
    int E)
{
    const int lane = threadIdx.x & 63;
    const int wave = threadIdx.x >> 6;
    const int c = lane & 15;   // edge-in-tile (A row m, C col n)
    const int g = lane >> 4;   // k-group

    const long e0 = (long)(blockIdx.x * 4 + wave) * 64;
    if (e0 >= E) return;       // wave-uniform (E % 64 == 0)

    // B fragments: W2 broadcast across columns. B[k][n] = W2[k] for all n.
    half8 Bw[2];
    #pragma unroll
    for (int kk = 0; kk < 2; kk++) {
        const float* wp = W2 + kk * 32 + g * 8;
        float4v w0 = *(const float4v*)wp;
        float4v w1 = *(const float4v*)(wp + 4);
        half8 B;
        B[0] = (_Float16)w0[0]; B[1] = (_Float16)w0[1];
        B[2] = (_Float16)w0[2]; B[3] = (_Float16)w0[3];
        B[4] = (_Float16)w1[0]; B[5] = (_Float16)w1[1];
        B[6] = (_Float16)w1[2]; B[7] = (_Float16)w1[3];
        Bw[kk] = B;
    }
    const float b2v = b2[0];

    // Index loads (8 dwords, coalesced) — all independent.
    int s[4], d[4];
    #pragma unroll
    for (int t = 0; t < 4; t++) {
        s[t] = ei[e0 + t * 16 + c];
        d[t] = ei[E + e0 + t * 16 + c];
    }

    // Gathers (16 x 16 B) — all independent, hoistable above compute.
    half8 av[4][2], bv[4][2];
    #pragma unroll
    for (int t = 0; t < 4; t++) {
        #pragma unroll
        for (int kk = 0; kk < 2; kk++) {
            av[t][kk] = *(const half8*)(Yab + (size_t)s[t] * FDIM + kk * 32 + g * 8);
            bv[t][kk] = *(const half8*)(Yab + (size_t)d[t] * FDIM + 64 + kk * 32 + g * 8);
        }
    }

    const half8 zero8 = (half8)(_Float16)0.0f;
    #pragma unroll
    for (int t = 0; t < 4; t++) {
        float4v C = (float4v){0.f, 0.f, 0.f, 0.f};
        #pragma unroll
        for (int kk = 0; kk < 2; kk++) {
            half8 H = av[t][kk] + bv[t][kk];          // v_pk_add_f16
            H = __builtin_elementwise_max(H, zero8);  // v_pk_max_f16 (relu)
            C = __builtin_amdgcn_mfma_f32_16x16x32_f16(H, Bw[kk], C, 0, 0, 0);
        }
        // Every column n holds the dot; C row m = g*4 + r = edge-in-tile.
        if (c == 0) {
            float4v o;
            #pragma unroll
            for (int r = 0; r < 4; r++) o[r] = C[r] + b2v;
            *(float4v*)(out + e0 + t * 16 + g * 4) = o;
        }
    }
}

// ---------------- fp32 fallback (ws too small; not expected) -----------------
__global__ __launch_bounds__(256) void edge_mlp_fp32_kernel(
    const float* __restrict__ x, const int* __restrict__ ei,
    const float* __restrict__ W1, const float* __restrict__ b1,
    const float* __restrict__ W2, const float* __restrict__ b2,
    float* __restrict__ out, int E)
{
    int e = blockIdx.x * blockDim.x + threadIdx.x;
    if (e >= E) return;
    int s = ei[e];
    int d = ei[E + e];
    const float* xs = x + (size_t)s * NDIM;
    const float* xd = x + (size_t)d * NDIM;
    float acc = b2[0];
    for (int j = 0; j < NDIM; j++) {
        float h = b1[j];
        for (int k = 0; k < NDIM; k++) {
            h += xs[k] * W1[j * FDIM + k] + xd[k] * W1[j * FDIM + 64 + k];
        }
        acc += W2[j] * (h > 0.f ? h : 0.f);
    }
    out[e] = acc;
}

extern "C" void kernel_launch(void* const* d_in, const int* in_sizes, int n_in,
                              void* d_out, int out_size, void* d_ws, size_t ws_size,
                              hipStream_t stream) {
    const float* x  = (const float*)d_in[0];
    const int*   ei = (const int*)d_in[1];
    const float* W1 = (const float*)d_in[2];
    const float* b1 = (const float*)d_in[3];
    const float* W2 = (const float*)d_in[4];
    const float* b2 = (const float*)d_in[5];
    float* out = (float*)d_out;
    const int E = out_size;
    const int N = in_sizes[0] / NDIM;

    const size_t wcomb_bytes = (size_t)FDIM * NDIM * sizeof(_Float16);  // 16 KB
    const size_t tbl_bytes   = (size_t)N * FDIM * sizeof(_Float16);     // 25.6 MB

    if (ws_size >= wcomb_bytes + tbl_bytes && (N % 16) == 0 && (E % 64) == 0) {
        _Float16* Wcomb = (_Float16*)d_ws;
        _Float16* Yab   = (_Float16*)((char*)d_ws + wcomb_bytes);

        prep_wcomb_kernel<<<(FDIM * NDIM + 255) / 256, 256, 0, stream>>>(W1, Wcomb);

        const int nblocks = (N + 63) / 64;
        node_gemm_kernel<<<nblocks, 256, 0, stream>>>(x, Wcomb, b1, Yab, N);

        const int eblocks = (E + 255) / 256;   // 4 waves x 64 edges per block
        edge_combine_kernel<<<eblocks, 256, 0, stream>>>(
            Yab, ei, W2, b2, out, E);
    } else {
        edge_mlp_fp32_kernel<<<(E + 255) / 256, 256, 0, stream>>>(
            x, ei, W1, b1, W2, b2, out, E);
    }
}

// Round 8
// 132.375 us; speedup vs baseline: 1.0189x; 1.0189x over previous
//
#include <hip/hip_runtime.h>

#define NDIM 64   // D
#define FDIM 128  // 2D
#define LSTRIDE 136  // LDS row stride in halfs (128 + 8 pad -> breaks pow2 banks)

typedef _Float16 half8  __attribute__((ext_vector_type(8)));
typedef _Float16 half4v __attribute__((ext_vector_type(4)));
typedef float    float4v __attribute__((ext_vector_type(4)));

// ---------------------------------------------------------------------------
// Prep: Wcomb[j][k] (f16, [128][64]) = j<64 ? W1[j][k] : W1[j-64][64+k]
// (UNCHANGED from round 6/7)
// ---------------------------------------------------------------------------
__global__ __launch_bounds__(256) void prep_wcomb_kernel(
    const float* __restrict__ W1, _Float16* __restrict__ Wcomb)
{
    int i = blockIdx.x * blockDim.x + threadIdx.x;   // 8192 = 128*64
    if (i >= FDIM * NDIM) return;
    int j = i >> 6;
    int k = i & 63;
    float v = (j < NDIM) ? W1[j * FDIM + k] : W1[(j - NDIM) * FDIM + NDIM + k];
    Wcomb[i] = (_Float16)v;
}

// ---------------------------------------------------------------------------
// Kernel 1 (v3): node half-layers via MFMA + LDS store-transpose epilogue.
//   Yab[n][j]    = b1[j] + sum_k x[n][k] * W1[j][k]        (j < 64)
//   Yab[n][64+j] =         sum_k x[n][k] * W1[j][64+k]
// MFMA part unchanged from R6. Epilogue now routes C through wave-private
// LDS so each global store instruction covers 4 complete node rows (1 KB
// contiguous) instead of 8x8B scattered across 16 rows.
// ---------------------------------------------------------------------------
__global__ __launch_bounds__(256) void node_gemm_kernel(
    const float* __restrict__ x,        // [N][64]
    const _Float16* __restrict__ Wcomb, // [128][64]
    const float* __restrict__ b1,       // [64]
    _Float16* __restrict__ Yab,         // [N][128]
    int N)
{
    __shared__ _Float16 lds[4][16 * LSTRIDE];   // per-wave 16 node rows

    const int wave = threadIdx.x >> 6;
    const int lane = threadIdx.x & 63;
    const int c = lane & 15;   // A: j-in-tile | B/C: node-in-tile
    const int g = lane >> 4;   // k-group / C row-group

    const int node0 = (blockIdx.x * 4 + wave) * 16;
    if (node0 >= N) return;    // wave-uniform (N % 16 == 0)

    // B fragments: x[node0+c][kk*32 + g*8 .. +8], f32 -> f16
    half8 Bf[2];
    #pragma unroll
    for (int kk = 0; kk < 2; kk++) {
        const float* bp = x + (size_t)(node0 + c) * NDIM + kk * 32 + g * 8;
        float4v b0 = *(const float4v*)bp;
        float4v b1v_ = *(const float4v*)(bp + 4);
        half8 B;
        B[0] = (_Float16)b0[0]; B[1] = (_Float16)b0[1];
        B[2] = (_Float16)b0[2]; B[3] = (_Float16)b0[3];
        B[4] = (_Float16)b1v_[0]; B[5] = (_Float16)b1v_[1];
        B[6] = (_Float16)b1v_[2]; B[7] = (_Float16)b1v_[3];
        Bf[kk] = B;
    }

    float4v C[8];
    #pragma unroll
    for (int mt = 0; mt < 8; mt++) C[mt] = (float4v){0.f, 0.f, 0.f, 0.f};

    #pragma unroll
    for (int kk = 0; kk < 2; kk++) {
        #pragma unroll
        for (int mt = 0; mt < 8; mt++) {
            half8 Af = *(const half8*)(Wcomb + (size_t)(mt * 16 + c) * NDIM
                                       + kk * 32 + g * 8);
            C[mt] = __builtin_amdgcn_mfma_f32_16x16x32_f16(Af, Bf[kk], C[mt], 0, 0, 0);
        }
    }

    // Epilogue A: +b1 (j<64), cvt f16, write to wave-private LDS.
    // Lane (c,g) holds j = mt*16 + g*4 + r for node c.
    #pragma unroll
    for (int mt = 0; mt < 8; mt++) {
        float4v badd = (float4v){0.f, 0.f, 0.f, 0.f};
        if (mt < 4) badd = *(const float4v*)(b1 + mt * 16 + g * 4);
        half4v o;
        #pragma unroll
        for (int r = 0; r < 4; r++) o[r] = (_Float16)(C[mt][r] + badd[r]);
        *(half4v*)&lds[wave][c * LSTRIDE + mt * 16 + g * 4] = o;
    }

    // Epilogue B: read back row-major, store 1 KB contiguous per instruction
    // (4 passes x 64 lanes x 16 B = 4 node rows per pass). Wave-private LDS,
    // no barrier needed; compiler inserts lgkmcnt waits for the RAW dep.
    #pragma unroll
    for (int p = 0; p < 4; p++) {
        const int node  = 4 * p + (lane >> 4);   // 0..15
        const int chunk = lane & 15;             // 16 B chunk within the row
        half8 v = *(const half8*)&lds[wave][node * LSTRIDE + chunk * 8];
        *(half8*)(Yab + (size_t)(node0 + node) * FDIM + chunk * 8) = v;
    }
}

// ---------------------------------------------------------------------------
// Kernel 2: per-edge combine, MFMA layer-2. (UNCHANGED from round 7)
//   out[e] = b2 + sum_j W2[j] * relu(Yab[s][j] + Yab[d][64+j])
// ---------------------------------------------------------------------------
__global__ __launch_bounds__(256) void edge_combine_kernel(
    const _Float16* __restrict__ Yab,  // [N][128]
    const int* __restrict__ ei,        // [2E]
    const float* __restrict__ W2,      // [64]
    const float* __restrict__ b2,      // [1]
    float* __restrict__ out,           // [E]
    int E)
{
    const int lane = threadIdx.x & 63;
    const int wave = threadIdx.x >> 6;
    const int c = lane & 15;   // edge-in-tile (A row m, C col n)
    const int g = lane >> 4;   // k-group

    const long e0 = (long)(blockIdx.x * 4 + wave) * 64;
    if (e0 >= E) return;       // wave-uniform (E % 64 == 0)

    half8 Bw[2];
    #pragma unroll
    for (int kk = 0; kk < 2; kk++) {
        const float* wp = W2 + kk * 32 + g * 8;
        float4v w0 = *(const float4v*)wp;
        float4v w1 = *(const float4v*)(wp + 4);
        half8 B;
        B[0] = (_Float16)w0[0]; B[1] = (_Float16)w0[1];
        B[2] = (_Float16)w0[2]; B[3] = (_Float16)w0[3];
        B[4] = (_Float16)w1[0]; B[5] = (_Float16)w1[1];
        B[6] = (_Float16)w1[2]; B[7] = (_Float16)w1[3];
        Bw[kk] = B;
    }
    const float b2v = b2[0];

    int s[4], d[4];
    #pragma unroll
    for (int t = 0; t < 4; t++) {
        s[t] = ei[e0 + t * 16 + c];
        d[t] = ei[E + e0 + t * 16 + c];
    }

    half8 av[4][2], bv[4][2];
    #pragma unroll
    for (int t = 0; t < 4; t++) {
        #pragma unroll
        for (int kk = 0; kk < 2; kk++) {
            av[t][kk] = *(const half8*)(Yab + (size_t)s[t] * FDIM + kk * 32 + g * 8);
            bv[t][kk] = *(const half8*)(Yab + (size_t)d[t] * FDIM + 64 + kk * 32 + g * 8);
        }
    }

    const half8 zero8 = (half8)(_Float16)0.0f;
    #pragma unroll
    for (int t = 0; t < 4; t++) {
        float4v C = (float4v){0.f, 0.f, 0.f, 0.f};
        #pragma unroll
        for (int kk = 0; kk < 2; kk++) {
            half8 H = av[t][kk] + bv[t][kk];          // v_pk_add_f16
            H = __builtin_elementwise_max(H, zero8);  // v_pk_max_f16 (relu)
            C = __builtin_amdgcn_mfma_f32_16x16x32_f16(H, Bw[kk], C, 0, 0, 0);
        }
        if (c == 0) {
            float4v o;
            #pragma unroll
            for (int r = 0; r < 4; r++) o[r] = C[r] + b2v;
            *(float4v*)(out + e0 + t * 16 + g * 4) = o;
        }
    }
}

// ---------------- fp32 fallback (ws too small; not expected) -----------------
__global__ __launch_bounds__(256) void edge_mlp_fp32_kernel(
    const float* __restrict__ x, const int* __restrict__ ei,
    const float* __restrict__ W1, const float* __restrict__ b1,
    const float* __restrict__ W2, const float* __restrict__ b2,
    float* __restrict__ out, int E)
{
    int e = blockIdx.x * blockDim.x + threadIdx.x;
    if (e >= E) return;
    int s = ei[e];
    int d = ei[E + e];
    const float* xs = x + (size_t)s * NDIM;
    const float* xd = x + (size_t)d * NDIM;
    float acc = b2[0];
    for (int j = 0; j < NDIM; j++) {
        float h = b1[j];
        for (int k = 0; k < NDIM; k++) {
            h += xs[k] * W1[j * FDIM + k] + xd[k] * W1[j * FDIM + 64 + k];
        }
        acc += W2[j] * (h > 0.f ? h : 0.f);
    }
    out[e] = acc;
}

extern "C" void kernel_launch(void* const* d_in, const int* in_sizes, int n_in,
                              void* d_out, int out_size, void* d_ws, size_t ws_size,
                              hipStream_t stream) {
    const float* x  = (const float*)d_in[0];
    const int*   ei = (const int*)d_in[1];
    const float* W1 = (const float*)d_in[2];
    const float* b1 = (const float*)d_in[3];
    const float* W2 = (const float*)d_in[4];
    const float* b2 = (const float*)d_in[5];
    float* out = (float*)d_out;
    const int E = out_size;
    const int N = in_sizes[0] / NDIM;

    const size_t wcomb_bytes = (size_t)FDIM * NDIM * sizeof(_Float16);  // 16 KB
    const size_t tbl_bytes   = (size_t)N * FDIM * sizeof(_Float16);     // 25.6 MB

    if (ws_size >= wcomb_bytes + tbl_bytes && (N % 16) == 0 && (E % 64) == 0) {
        _Float16* Wcomb = (_Float16*)d_ws;
        _Float16* Yab   = (_Float16*)((char*)d_ws + wcomb_bytes);

        prep_wcomb_kernel<<<(FDIM * NDIM + 255) / 256, 256, 0, stream>>>(W1, Wcomb);

        const int nblocks = (N + 63) / 64;
        node_gemm_kernel<<<nblocks, 256, 0, stream>>>(x, Wcomb, b1, Yab, N);

        const int eblocks = (E + 255) / 256;   // 4 waves x 64 edges per block
        edge_combine_kernel<<<eblocks, 256, 0, stream>>>(
            Yab, ei, W2, b2, out, E);
    } else {
        edge_mlp_fp32_kernel<<<(E + 255) / 256, 256, 0, stream>>>(
            x, ei, W1, b1, W2, b2, out, E);
    }
}

// Round 9
// 132.101 us; speedup vs baseline: 1.0210x; 1.0021x over previous
//
#include <hip/hip_runtime.h>

#define NDIM 64   // D
#define FDIM 128  // 2D
#define LSTRIDE 136  // LDS row stride in halfs (128 + 8 pad -> breaks pow2 banks)

typedef _Float16 half8  __attribute__((ext_vector_type(8)));
typedef _Float16 half4v __attribute__((ext_vector_type(4)));
typedef float    float4v __attribute__((ext_vector_type(4)));

// ---------------------------------------------------------------------------
// Prep: Wcomb[j][k] (f16, [128][64]) = j<64 ? W1[j][k] : W1[j-64][64+k]
// (UNCHANGED)
// ---------------------------------------------------------------------------
__global__ __launch_bounds__(256) void prep_wcomb_kernel(
    const float* __restrict__ W1, _Float16* __restrict__ Wcomb)
{
    int i = blockIdx.x * blockDim.x + threadIdx.x;   // 8192 = 128*64
    if (i >= FDIM * NDIM) return;
    int j = i >> 6;
    int k = i & 63;
    float v = (j < NDIM) ? W1[j * FDIM + k] : W1[(j - NDIM) * FDIM + NDIM + k];
    Wcomb[i] = (_Float16)v;
}

// ---------------------------------------------------------------------------
// Kernel 1 (v4): node half-layers via MFMA; 32 nodes per wave (2 tiles
// sharing each Wcomb A-fragment), nt x-loads, LDS store-transpose epilogue.
//   Yab[n][j]    = b1[j] + sum_k x[n][k] * W1[j][k]        (j < 64)
//   Yab[n][64+j] =         sum_k x[n][k] * W1[j][64+k]
// ---------------------------------------------------------------------------
__global__ __launch_bounds__(256) void node_gemm_kernel(
    const float* __restrict__ x,        // [N][64]
    const _Float16* __restrict__ Wcomb, // [128][64]
    const float* __restrict__ b1,       // [64]
    _Float16* __restrict__ Yab,         // [N][128]
    int N)
{
    __shared__ _Float16 lds[4][16 * LSTRIDE];   // per-wave transpose slice

    const int wave = threadIdx.x >> 6;
    const int lane = threadIdx.x & 63;
    const int c = lane & 15;   // A: j-in-tile | B/C: node-in-tile
    const int g = lane >> 4;   // k-group / C row-group

    const int node0 = (blockIdx.x * 4 + wave) * 32;   // 32 nodes per wave
    if (node0 >= N) return;    // wave-uniform; N % 32 == 0 -> both tiles valid

    // B fragments for both 16-node tiles: x rows, f32 nt loads -> f16
    half8 Bf[2][2];   // [tile][kk]
    #pragma unroll
    for (int t2 = 0; t2 < 2; t2++) {
        #pragma unroll
        for (int kk = 0; kk < 2; kk++) {
            const float* bp = x + (size_t)(node0 + t2 * 16 + c) * NDIM
                              + kk * 32 + g * 8;
            float4v b0 = __builtin_nontemporal_load((const float4v*)bp);
            float4v b1v_ = __builtin_nontemporal_load((const float4v*)(bp + 4));
            half8 B;
            B[0] = (_Float16)b0[0]; B[1] = (_Float16)b0[1];
            B[2] = (_Float16)b0[2]; B[3] = (_Float16)b0[3];
            B[4] = (_Float16)b1v_[0]; B[5] = (_Float16)b1v_[1];
            B[6] = (_Float16)b1v_[2]; B[7] = (_Float16)b1v_[3];
            Bf[t2][kk] = B;
        }
    }

    float4v C[2][8];
    #pragma unroll
    for (int t2 = 0; t2 < 2; t2++)
        #pragma unroll
        for (int mt = 0; mt < 8; mt++)
            C[t2][mt] = (float4v){0.f, 0.f, 0.f, 0.f};

    #pragma unroll
    for (int kk = 0; kk < 2; kk++) {
        #pragma unroll
        for (int mt = 0; mt < 8; mt++) {
            half8 Af = *(const half8*)(Wcomb + (size_t)(mt * 16 + c) * NDIM
                                       + kk * 32 + g * 8);
            C[0][mt] = __builtin_amdgcn_mfma_f32_16x16x32_f16(Af, Bf[0][kk], C[0][mt], 0, 0, 0);
            C[1][mt] = __builtin_amdgcn_mfma_f32_16x16x32_f16(Af, Bf[1][kk], C[1][mt], 0, 0, 0);
        }
    }

    // Epilogue per tile: +b1 (j<64), cvt f16, LDS transpose, 1KB-coalesced
    // stores. Tile 1 reuses the wave-private slice (DS ops in-order per wave).
    #pragma unroll
    for (int t2 = 0; t2 < 2; t2++) {
        #pragma unroll
        for (int mt = 0; mt < 8; mt++) {
            float4v badd = (float4v){0.f, 0.f, 0.f, 0.f};
            if (mt < 4) badd = *(const float4v*)(b1 + mt * 16 + g * 4);
            half4v o;
            #pragma unroll
            for (int r = 0; r < 4; r++) o[r] = (_Float16)(C[t2][mt][r] + badd[r]);
            *(half4v*)&lds[wave][c * LSTRIDE + mt * 16 + g * 4] = o;
        }
        #pragma unroll
        for (int p = 0; p < 4; p++) {
            const int node  = 4 * p + (lane >> 4);
            const int chunk = lane & 15;
            half8 v = *(const half8*)&lds[wave][node * LSTRIDE + chunk * 8];
            *(half8*)(Yab + (size_t)(node0 + t2 * 16 + node) * FDIM + chunk * 8) = v;
        }
    }
}

// ---------------------------------------------------------------------------
// Kernel 2: per-edge combine, MFMA layer-2. (R7 structure + nt ei loads and
// nt out stores to keep L2 free for the Yab gather table)
//   out[e] = b2 + sum_j W2[j] * relu(Yab[s][j] + Yab[d][64+j])
// ---------------------------------------------------------------------------
__global__ __launch_bounds__(256) void edge_combine_kernel(
    const _Float16* __restrict__ Yab,  // [N][128]
    const int* __restrict__ ei,        // [2E]
    const float* __restrict__ W2,      // [64]
    const float* __restrict__ b2,      // [1]
    float* __restrict__ out,           // [E]
    int E)
{
    const int lane = threadIdx.x & 63;
    const int wave = threadIdx.x >> 6;
    const int c = lane & 15;   // edge-in-tile (A row m, C col n)
    const int g = lane >> 4;   // k-group

    const long e0 = (long)(blockIdx.x * 4 + wave) * 64;
    if (e0 >= E) return;       // wave-uniform (E % 64 == 0)

    half8 Bw[2];
    #pragma unroll
    for (int kk = 0; kk < 2; kk++) {
        const float* wp = W2 + kk * 32 + g * 8;
        float4v w0 = *(const float4v*)wp;
        float4v w1 = *(const float4v*)(wp + 4);
        half8 B;
        B[0] = (_Float16)w0[0]; B[1] = (_Float16)w0[1];
        B[2] = (_Float16)w0[2]; B[3] = (_Float16)w0[3];
        B[4] = (_Float16)w1[0]; B[5] = (_Float16)w1[1];
        B[6] = (_Float16)w1[2]; B[7] = (_Float16)w1[3];
        Bw[kk] = B;
    }
    const float b2v = b2[0];

    int s[4], d[4];
    #pragma unroll
    for (int t = 0; t < 4; t++) {
        s[t] = __builtin_nontemporal_load(ei + e0 + t * 16 + c);
        d[t] = __builtin_nontemporal_load(ei + E + e0 + t * 16 + c);
    }

    half8 av[4][2], bv[4][2];
    #pragma unroll
    for (int t = 0; t < 4; t++) {
        #pragma unroll
        for (int kk = 0; kk < 2; kk++) {
            av[t][kk] = *(const half8*)(Yab + (size_t)s[t] * FDIM + kk * 32 + g * 8);
            bv[t][kk] = *(const half8*)(Yab + (size_t)d[t] * FDIM + 64 + kk * 32 + g * 8);
        }
    }

    const half8 zero8 = (half8)(_Float16)0.0f;
    #pragma unroll
    for (int t = 0; t < 4; t++) {
        float4v C = (float4v){0.f, 0.f, 0.f, 0.f};
        #pragma unroll
        for (int kk = 0; kk < 2; kk++) {
            half8 H = av[t][kk] + bv[t][kk];          // v_pk_add_f16
            H = __builtin_elementwise_max(H, zero8);  // v_pk_max_f16 (relu)
            C = __builtin_amdgcn_mfma_f32_16x16x32_f16(H, Bw[kk], C, 0, 0, 0);
        }
        if (c == 0) {
            float4v o;
            #pragma unroll
            for (int r = 0; r < 4; r++) o[r] = C[r] + b2v;
            __builtin_nontemporal_store(o, (float4v*)(out + e0 + t * 16 + g * 4));
        }
    }
}

// ---------------- fp32 fallback (ws too small; not expected) -----------------
__global__ __launch_bounds__(256) void edge_mlp_fp32_kernel(
    const float* __restrict__ x, const int* __restrict__ ei,
    const float* __restrict__ W1, const float* __restrict__ b1,
    const float* __restrict__ W2, const float* __restrict__ b2,
    float* __restrict__ out, int E)
{
    int e = blockIdx.x * blockDim.x + threadIdx.x;
    if (e >= E) return;
    int s = ei[e];
    int d = ei[E + e];
    const float* xs = x + (size_t)s * NDIM;
    const float* xd = x + (size_t)d * NDIM;
    float acc = b2[0];
    for (int j = 0; j < NDIM; j++) {
        float h = b1[j];
        for (int k = 0; k < NDIM; k++) {
            h += xs[k] * W1[j * FDIM + k] + xd[k] * W1[j * FDIM + 64 + k];
        }
        acc += W2[j] * (h > 0.f ? h : 0.f);
    }
    out[e] = acc;
}

extern "C" void kernel_launch(void* const* d_in, const int* in_sizes, int n_in,
                              void* d_out, int out_size, void* d_ws, size_t ws_size,
                              hipStream_t stream) {
    const float* x  = (const float*)d_in[0];
    const int*   ei = (const int*)d_in[1];
    const float* W1 = (const float*)d_in[2];
    const float* b1 = (const float*)d_in[3];
    const float* W2 = (const float*)d_in[4];
    const float* b2 = (const float*)d_in[5];
    float* out = (float*)d_out;
    const int E = out_size;
    const int N = in_sizes[0] / NDIM;

    const size_t wcomb_bytes = (size_t)FDIM * NDIM * sizeof(_Float16);  // 16 KB
    const size_t tbl_bytes   = (size_t)N * FDIM * sizeof(_Float16);     // 25.6 MB

    if (ws_size >= wcomb_bytes + tbl_bytes && (N % 32) == 0 && (E % 64) == 0) {
        _Float16* Wcomb = (_Float16*)d_ws;
        _Float16* Yab   = (_Float16*)((char*)d_ws + wcomb_bytes);

        prep_wcomb_kernel<<<(FDIM * NDIM + 255) / 256, 256, 0, stream>>>(W1, Wcomb);

        const int nblocks = (N + 127) / 128;   // 4 waves x 32 nodes per block
        node_gemm_kernel<<<nblocks, 256, 0, stream>>>(x, Wcomb, b1, Yab, N);

        const int eblocks = (E + 255) / 256;   // 4 waves x 64 edges per block
        edge_combine_kernel<<<eblocks, 256, 0, stream>>>(
            Yab, ei, W2, b2, out, E);
    } else {
        edge_mlp_fp32_kernel<<<(E + 255) / 256, 256, 0, stream>>>(
            x, ei, W1, b1, W2, b2, out, E);
    }
}